// Round 9
// baseline (401.467 us; speedup 1.0000x reference)
//
#include <hip/hip_runtime.h>

typedef float v2f __attribute__((ext_vector_type(2)));

#define T_LEN 2048
#define BB    128
#define CC    128
#define EE    32
#define HH    64
#define PRED  336
#define CH    16          // steps per ring chunk
#define NCH   21          // 21*16 = 336

#define PADT(t) ((t) + ((t) >> 6))

__device__ __forceinline__ v2f mk2(float a, float b) { v2f t; t.x = a; t.y = b; return t; }
__device__ __forceinline__ float rl(float v, int j) {
    return __int_as_float(__builtin_amdgcn_readlane(__float_as_int(v), j));
}

#define REP64(F) F(0) F(1) F(2) F(3) F(4) F(5) F(6) F(7) F(8) F(9) \
    F(10) F(11) F(12) F(13) F(14) F(15) F(16) F(17) F(18) F(19) \
    F(20) F(21) F(22) F(23) F(24) F(25) F(26) F(27) F(28) F(29) \
    F(30) F(31) F(32) F(33) F(34) F(35) F(36) F(37) F(38) F(39) \
    F(40) F(41) F(42) F(43) F(44) F(45) F(46) F(47) F(48) F(49) \
    F(50) F(51) F(52) F(53) F(54) F(55) F(56) F(57) F(58) F(59) \
    F(60) F(61) F(62) F(63)

// ---------------------------------------------------------------------------
// ONE kernel, one block (256 thr = 4 waves) per batch element.
// Prologue: channel-0 extract, 7-tap MA, 4 encoder tanh-GEMVs -> s_v[32];
// cooperative build of u-space constant matrices into LDS:
//   s_Mag[k][h] = (W_o@[W_in|W_g])[k][h],  s_Mr[k][c] = (W_o@Wr)[k][c].
// Each scan wave loads its M-columns into 64 NAMED scalar registers and an
// asm memory-clobber fence pins them there (R5-R8 lesson: the compiler
// rematerializes LDS/array loads back into the loop -> VGPR_Count stayed
// ~110-132 and every step re-read 512B of M; sinking a load across a
// memory clobber is illegal, so this forces register residency).
// Scan (u-space linear recurrence; logmap0(expmap0(v)) == v):
//   wave 0: u_h = silu(A_h)*sigm(G_h); AG += u@M_ag + c_ag via v_readlane
//           register-crossbar (zero LDS on the chain); u posted to ring.
//   waves 1,2: P_c += u@M_r[:,c] + c_r; store P (= pred_n). Chunked
//           double-buffered ring, 1 barrier / 16 steps. wave 3: companion.
// ---------------------------------------------------------------------------
__global__ __launch_bounds__(256, 1) void fused_kernel(
    const float* __restrict__ x,
    const float* __restrict__ WeT,  const float* __restrict__ beT,
    const float* __restrict__ WeW,  const float* __restrict__ beW,
    const float* __restrict__ WeD,  const float* __restrict__ beD,
    const float* __restrict__ WeR,  const float* __restrict__ beR,
    const float* __restrict__ Wdin, const float* __restrict__ bdin,
    const float* __restrict__ Wdg,  const float* __restrict__ bdg,
    const float* __restrict__ Wdo,  const float* __restrict__ bdo,
    const float* __restrict__ Wr,   const float* __restrict__ br,
    float* __restrict__ out)
{
    __shared__ __align__(16) float s_x   [T_LEN + 6];
    __shared__ __align__(16) float s_tr  [T_LEN + 32];
    __shared__ __align__(16) float s_rs  [T_LEN + 32];
    __shared__ __align__(16) float s_part[4][32][32];
    __shared__ __align__(16) float s_red [4][32];
    __shared__ __align__(16) float s_v   [EE];
    __shared__ __align__(16) v2f   s_Mag [HH * HH];      // 32 KB
    __shared__ __align__(16) float s_Mr  [HH * CC];      // 32 KB
    __shared__ __align__(16) float s_u   [2][CH][HH];    //  8 KB ring

    const int tid  = threadIdx.x;
    const int wid  = tid >> 6;
    const int lane = tid & 63;
    const int b    = blockIdx.x;
    const float* xb = x + (size_t)b * T_LEN * CC;

    for (int i = tid; i < T_LEN + 6; i += 256) {
        int t = i - 3;
        t = t < 0 ? 0 : (t > T_LEN - 1 ? T_LEN - 1 : t);
        s_x[i] = xb[(size_t)t * CC];
    }
    __syncthreads();

    for (int t = tid; t < T_LEN; t += 256) {
        float s = 0.f;
        #pragma unroll
        for (int j = 0; j < 7; ++j) s += s_x[t + j];
        float tm = s * (1.0f / 7.0f);
        s_tr[PADT(t)] = tm;
        s_rs[PADT(t)] = s_x[t + 3] - tm;
    }
    __syncthreads();

    {   // 4 encoder GEMV partials: thread = (e-quad eq, t-group tg of 32)
        const int eq = tid & 7, tg = tid >> 3;
        float4 aT = {0,0,0,0}, aW = aT, aD = aT, aR = aT;
        const float4* WT4 = (const float4*)WeT;
        const float4* WW4 = (const float4*)WeW;
        const float4* WD4 = (const float4*)WeD;
        const float4* WR4 = (const float4*)WeR;
        #pragma unroll 4
        for (int j = 0; j < 64; ++j) {
            int t  = tg * 64 + j;
            int wi = t * 8 + eq;
            float trv = s_tr[PADT(t)], rsv = s_rs[PADT(t)];
            float4 w;
            w = WT4[wi]; aT.x += trv*w.x; aT.y += trv*w.y; aT.z += trv*w.z; aT.w += trv*w.w;
            w = WW4[wi]; aW.x += rsv*w.x; aW.y += rsv*w.y; aW.z += rsv*w.z; aW.w += rsv*w.w;
            w = WD4[wi]; aD.x += rsv*w.x; aD.y += rsv*w.y; aD.z += rsv*w.z; aD.w += rsv*w.w;
            w = WR4[wi]; aR.x += rsv*w.x; aR.y += rsv*w.y; aR.z += rsv*w.z; aR.w += rsv*w.w;
        }
        ((float4*)&s_part[0][tg][0])[eq] = aT;
        ((float4*)&s_part[1][tg][0])[eq] = aW;
        ((float4*)&s_part[2][tg][0])[eq] = aD;
        ((float4*)&s_part[3][tg][0])[eq] = aR;
    }
    __syncthreads();

    if (tid < 128) {
        const int m = tid >> 5, e = tid & 31;
        float s = 0.f;
        #pragma unroll
        for (int g = 0; g < 32; ++g) s += s_part[m][g][e];
        s_red[m][e] = s;
    }
    __syncthreads();

    if (tid < EE) {
        s_v[tid] = tanhf(s_red[0][tid] + beT[tid])
                 + tanhf(s_red[1][tid] + beW[tid])
                 + tanhf(s_red[2][tid] + beD[tid])
                 + tanhf(s_red[3][tid] + beR[tid]);
    }

    {   // cooperative M-build into LDS
        const int h = tid & 63, kg = tid >> 6;
        for (int kk = 0; kk < 16; ++kk) {
            int k = kg * 16 + kk;
            float mi = 0.f, mg = 0.f;
            for (int e = 0; e < EE; ++e) {
                float wo = Wdo[k * EE + e];
                mi += wo * Wdin[e * HH + h];
                mg += wo * Wdg [e * HH + h];
            }
            s_Mag[k * HH + h] = mk2(mi, mg);
        }
        const int c = tid & 127, kg2 = tid >> 7;
        for (int kk = 0; kk < 32; ++kk) {
            int k = kg2 * 32 + kk;
            float m = 0.f;
            for (int e = 0; e < EE; ++e) m += Wdo[k * EE + e] * Wr[e * CC + c];
            s_Mr[k * CC + c] = m;
        }
    }
    __syncthreads();

    if (wid == 0) {
        // ================= producer: A,G state for h = lane =================
        #define MA_DECL(j) v2f ma##j = s_Mag[(j) * HH + lane];
        REP64(MA_DECL)
        #undef MA_DECL

        v2f c_ag = mk2(0.f, 0.f);
        v2f ag   = mk2(bdin[lane], bdg[lane]);
        #pragma unroll
        for (int e = 0; e < EE; ++e) {
            v2f w = mk2(Wdin[e * HH + lane], Wdg[e * HH + lane]);
            c_ag += bdo[e] * w;
            ag   += s_v[e] * w;
        }
        asm volatile("" ::: "memory");   // pin ma0..ma63 in VGPRs (no remat)

        for (int c = 0; c <= NCH; ++c) {
            if (c < NCH) {
                float* ring = &s_u[c & 1][0][0];
                for (int i = 0; i < CH; ++i) {
                    float a = ag.x, g = ag.y;
                    float u = a * __builtin_amdgcn_rcpf(
                        (1.f + __expf(-a)) * (1.f + __expf(-g)));
                    ring[i * HH + lane] = u;      // posted; off the chain

                    v2f acc0 = c_ag, acc1 = mk2(0.f, 0.f),
                        acc2 = acc1, acc3 = acc1;
                    #define GQ(j0, j1, j2, j3) \
                        acc0 += rl(u, j0) * ma##j0; \
                        acc1 += rl(u, j1) * ma##j1; \
                        acc2 += rl(u, j2) * ma##j2; \
                        acc3 += rl(u, j3) * ma##j3;
                    GQ( 0, 1, 2, 3)  GQ( 4, 5, 6, 7)  GQ( 8, 9,10,11)
                    GQ(12,13,14,15)  GQ(16,17,18,19)  GQ(20,21,22,23)
                    GQ(24,25,26,27)  GQ(28,29,30,31)  GQ(32,33,34,35)
                    GQ(36,37,38,39)  GQ(40,41,42,43)  GQ(44,45,46,47)
                    GQ(48,49,50,51)  GQ(52,53,54,55)  GQ(56,57,58,59)
                    GQ(60,61,62,63)
                    #undef GQ
                    ag += (acc0 + acc1) + (acc2 + acc3);
                }
            }
            __syncthreads();
        }
    } else if (wid <= 2) {
        // ============ consumer: P state (pred) for channel c0 ===============
        const int c0 = (wid - 1) * 64 + lane;
        #define MR_DECL(j) float mr##j = s_Mr[(j) * CC + c0];
        REP64(MR_DECL)
        #undef MR_DECL

        float c_r = 0.f, P = br[c0];
        #pragma unroll
        for (int e = 0; e < EE; ++e) {
            float w = Wr[e * CC + c0];
            c_r += bdo[e] * w;
            P   += s_v[e] * w;            // P_{-1} = tv0@Wr + br
        }
        asm volatile("" ::: "memory");   // pin mr0..mr63 in VGPRs

        float* outb = out + (size_t)b * PRED * CC + c0;

        for (int c = 0; c <= NCH; ++c) {
            if (c > 0) {
                const float* ring = &s_u[(c - 1) & 1][0][0];
                const int n0 = (c - 1) * CH;
                for (int i = 0; i < CH; ++i) {
                    float a0 = c_r, a1 = 0.f, a2 = 0.f, a3 = 0.f;
                    const float4* u4 = (const float4*)(ring + i * HH);
                    #define CQ(k, j0, j1, j2, j3) { \
                        float4 q = u4[k]; \
                        a0 += q.x * mr##j0; a1 += q.y * mr##j1; \
                        a2 += q.z * mr##j2; a3 += q.w * mr##j3; }
                    CQ( 0,  0, 1, 2, 3)  CQ( 1,  4, 5, 6, 7)
                    CQ( 2,  8, 9,10,11)  CQ( 3, 12,13,14,15)
                    CQ( 4, 16,17,18,19)  CQ( 5, 20,21,22,23)
                    CQ( 6, 24,25,26,27)  CQ( 7, 28,29,30,31)
                    CQ( 8, 32,33,34,35)  CQ( 9, 36,37,38,39)
                    CQ(10, 40,41,42,43)  CQ(11, 44,45,46,47)
                    CQ(12, 48,49,50,51)  CQ(13, 52,53,54,55)
                    CQ(14, 56,57,58,59)  CQ(15, 60,61,62,63)
                    #undef CQ
                    P += (a0 + a1) + (a2 + a3);
                    outb[(size_t)(n0 + i) * CC] = P;
                }
            }
            __syncthreads();
        }
    } else {
        for (int c = 0; c <= NCH; ++c) __syncthreads();
    }
}

extern "C" void kernel_launch(void* const* d_in, const int* in_sizes, int n_in,
                              void* d_out, int out_size, void* d_ws, size_t ws_size,
                              hipStream_t stream)
{
    const float* x    = (const float*)d_in[0];
    const float* WeT  = (const float*)d_in[1];
    const float* beT  = (const float*)d_in[2];
    const float* WeW  = (const float*)d_in[3];
    const float* beW  = (const float*)d_in[4];
    const float* WeD  = (const float*)d_in[5];
    const float* beD  = (const float*)d_in[6];
    const float* WeR  = (const float*)d_in[7];
    const float* beR  = (const float*)d_in[8];
    const float* Wdin = (const float*)d_in[9];
    const float* bdin = (const float*)d_in[10];
    const float* Wdg  = (const float*)d_in[11];
    const float* bdg  = (const float*)d_in[12];
    const float* Wdo  = (const float*)d_in[13];
    const float* bdo  = (const float*)d_in[14];
    const float* Wr   = (const float*)d_in[15];
    const float* br   = (const float*)d_in[16];

    fused_kernel<<<BB, 256, 0, stream>>>(x, WeT, beT, WeW, beW, WeD, beD,
                                         WeR, beR, Wdin, bdin, Wdg, bdg,
                                         Wdo, bdo, Wr, br, (float*)d_out);
}